// Round 5
// baseline (288.808 us; speedup 1.0000x reference)
//
#include <hip/hip_runtime.h>

#define BB 8
#define CC 64
#define OO 64
#define NN 16384
#define MMODE 32
#define JJ 128
#define SFAC 64.0f
#define NBLK 512u

typedef __attribute__((ext_vector_type(8))) short short8;   // 8 bf16 = 4 VGPRs (MFMA A/B frag)
typedef __attribute__((ext_vector_type(4))) float f32x4;    // MFMA C/D frag

static __device__ __forceinline__ unsigned short f2bf(float f) {
  unsigned u = __float_as_uint(f);
  u += 0x7FFF + ((u >> 16) & 1);   // RTNE
  return (unsigned short)(u >> 16);
}
static __device__ __forceinline__ unsigned pack2(float a, float b) {
  return (unsigned)f2bf(a) | ((unsigned)f2bf(b) << 16);
}
// v_sin_f32/v_cos_f32 take REVOLUTIONS (D = sin(2*pi*S0))
static __device__ __forceinline__ float sin2pi(float x) { return __builtin_amdgcn_sinf(x); }
static __device__ __forceinline__ float cos2pi(float x) { return __builtin_amdgcn_cosf(x); }

// grid barrier: 512 blocks co-resident (2/CU). One counter, monotone targets.
static __device__ __forceinline__ void gbar(unsigned* ctr, unsigned target) {
  __syncthreads();                       // drains vmcnt: all stores issued & complete
  if (threadIdx.x == 0) {
    __threadfence();                     // agent-scope release: L2 writeback for cross-XCD
    __hip_atomic_fetch_add(ctr, 1u, __ATOMIC_ACQ_REL, __HIP_MEMORY_SCOPE_AGENT);
    while (__hip_atomic_load(ctr, __ATOMIC_ACQUIRE, __HIP_MEMORY_SCOPE_AGENT) < target) {}
    __threadfence();                     // acquire side: invalidate stale lines
  }
  __syncthreads();
}

// ws layout (floats):
//   part [B][64][J][C] at 0          (4,194,304 floats, 16 MB)
//   A    [B][O][J]     at 4,194,304  (65,536 floats)
//   ctr  (unsigned)    at 4,259,840  (memset to 0 each launch)

__global__ __launch_bounds__(256, 2) void fused_kernel(
    const float* __restrict__ x, const float* __restrict__ x_in,
    const float* __restrict__ x_out, const float* __restrict__ w1,
    const float* __restrict__ w2, float* __restrict__ out,
    float* __restrict__ part, float* __restrict__ A, unsigned* __restrict__ ctr) {
  __shared__ __attribute__((aligned(16))) unsigned char smem[37376];
  const int t = threadIdx.x;
  const int blk = blockIdx.x;
  const int b = blk >> 6, sl = blk & 63;

  // ================= phase 1: forward NUFFT partials =================
  // part[b,sl,j,c] = sum_{n in 256-slab} bas[j,n] * x[c,n]
  {
    short* bas = (short*)smem;                // [j][n] bf16, stride 72 (18432 B)
    short* xs  = bas + JJ * 72;               // [c][n] bf16 (9216 B)
    float* ps  = (float*)(xs + 64 * 72);      // x_in slab [256 n][2] (2048 B)
    const int n0 = sl * 256;

    if (t < 128) {
      const float4 v = *(const float4*)&x_in[((size_t)b * NN + n0) * 2 + t * 4];
      *(float4*)&ps[t * 4] = v;
    }
    const int xc = t >> 2, xq = t & 3;
    const float* xbase = x + ((size_t)(b * CC + xc)) * NN + n0;
    float4 cur[4];
#pragma unroll
    for (int k = 0; k < 4; ++k) cur[k] = *(const float4*)&xbase[(k * 4 + xq) * 4];

    const int w = t >> 6, L = t & 63;
    const int q4 = L >> 4, l15 = L & 15;
    f32x4 acc[8];
#pragma unroll
    for (int i = 0; i < 8; ++i) acc[i] = (f32x4){0.f, 0.f, 0.f, 0.f};

    __syncthreads();  // ps visible

    for (int s = 0; s < 4; ++s) {
#pragma unroll
      for (int k = 0; k < 4; ++k)
        *(uint2*)&xs[xc * 72 + (k * 4 + xq) * 4] =
            make_uint2(pack2(cur[k].x, cur[k].y), pack2(cur[k].z, cur[k].w));
      if (s < 3) {
#pragma unroll
        for (int k = 0; k < 4; ++k)
          cur[k] = *(const float4*)&xbase[(s + 1) * 64 + (k * 4 + xq) * 4];
      }
      // basis: exp(-i*2pi*m*p)
#pragma unroll
      for (int ti = 0; ti < 2; ++ti) {
        const int tau = t + ti * 256;
        const int ng = tau & 7, mm = tau >> 3;
        const int br = mm >> 5, m = mm & 31;
        const float fm = (float)m;
        union { unsigned short u[8]; uint4 v; } R, I;
#pragma unroll
        for (int k = 0; k < 8; ++k) {
          const float p = ps[(s * 64 + ng * 8 + k) * 2 + br];
          float rev = fm * p;
          rev -= floorf(rev);
          R.u[k] = f2bf(cos2pi(rev));
          I.u[k] = f2bf(-sin2pi(rev));
        }
        const int row = br * 64 + 2 * m;
        *(uint4*)&bas[row * 72 + ng * 8]       = R.v;
        *(uint4*)&bas[(row + 1) * 72 + ng * 8] = I.v;
      }
      __syncthreads();
#pragma unroll
      for (int ks = 0; ks < 2; ++ks) {
        const int ko = ks * 32 + q4 * 8;
        const short8 a0 = *(const short8*)&bas[(w * 32 + l15) * 72 + ko];
        const short8 a1 = *(const short8*)&bas[(w * 32 + 16 + l15) * 72 + ko];
#pragma unroll
        for (int ct = 0; ct < 4; ++ct) {
          const short8 bv = *(const short8*)&xs[(ct * 16 + l15) * 72 + ko];
          acc[ct]     = __builtin_amdgcn_mfma_f32_16x16x32_bf16(a0, bv, acc[ct], 0, 0, 0);
          acc[4 + ct] = __builtin_amdgcn_mfma_f32_16x16x32_bf16(a1, bv, acc[4 + ct], 0, 0, 0);
        }
      }
      __syncthreads();
    }
    // non-atomic partial store. C/D: col(c)=lane&15, row(j)=q4*4+reg
    float* pp = part + (size_t)(b * 64 + sl) * JJ * CC;
#pragma unroll
    for (int ai = 0; ai < 2; ++ai)
#pragma unroll
      for (int ct = 0; ct < 4; ++ct) {
        const f32x4 v = acc[ai * 4 + ct];
#pragma unroll
        for (int r = 0; r < 4; ++r)
          pp[(w * 32 + ai * 16 + q4 * 4 + r) * CC + ct * 16 + l15] = v[r];
      }
  }

  gbar(ctr, NBLK);

  // ================= phase 2: slab reduction + mode mixing =================
  // one task per block: (m, branch, b2)
  {
    float* red = (float*)smem;     // [8][64]
    float* fre = red + 512;        // [64]
    float* fim = fre + 64;         // [64]
    const int m = blk & 31, branch = (blk >> 5) & 1, b2 = blk >> 6;
    const int c = t & 63, g = t >> 6;
    const int jb = branch * 64 + 2 * m;
    float pre = 0.f, pim = 0.f;
#pragma unroll
    for (int k = 0; k < 16; ++k) {
      const int sl2 = g + 4 * k;
      const float* pp = part + (size_t)(b2 * 64 + sl2) * JJ * CC;
      pre += pp[jb * CC + c];
      pim += pp[(jb + 1) * CC + c];
    }
    red[(g * 2) * 64 + c] = pre;
    red[(g * 2 + 1) * 64 + c] = pim;
    __syncthreads();
    if (t < 64) {
      fre[t] = red[0 * 64 + t] + red[2 * 64 + t] + red[4 * 64 + t] + red[6 * 64 + t];
      fim[t] = red[1 * 64 + t] + red[3 * 64 + t] + red[5 * 64 + t] + red[7 * 64 + t];
    }
    __syncthreads();
    const float* w = branch ? w2 : w1;  // [i][o][m][2]
    float ar = 0.f, ai = 0.f;
#pragma unroll 4
    for (int ii = 0; ii < 16; ++ii) {
      const int i = g * 16 + ii;
      const float2 wv = *(const float2*)&w[(((size_t)i * 64 + c) * MMODE + m) * 2];
      ar += fre[i] * wv.x - fim[i] * wv.y;
      ai += fre[i] * wv.y + fim[i] * wv.x;
    }
    __syncthreads();
    red[(g * 2) * 64 + c] = ar;
    red[(g * 2 + 1) * 64 + c] = ai;
    __syncthreads();
    if (t < 64) {
      const float sr = red[0 * 64 + t] + red[2 * 64 + t] + red[4 * 64 + t] + red[6 * 64 + t];
      const float si = red[1 * 64 + t] + red[3 * 64 + t] + red[5 * 64 + t] + red[7 * 64 + t];
      // fold scale S=64 and Re(): out = A_re*cos + A_im*sin
      *(float2*)&A[((size_t)b2 * OO + t) * JJ + jb] = make_float2(SFAC * sr, -SFAC * si);
    }
  }

  gbar(ctr, 2u * NBLK);

  // ================= phase 3: inverse NUFFT =================
  // out[b,o,n] = sum_j A[o,j] * bas[n,j]
  {
    short* As_s = (short*)smem;                 // [o][j] bf16, stride 136 (17408 B)
    short* basn = As_s + OO * 136;              // [n][j] bf16 (17408 B)
    float* psI  = (float*)(basn + 64 * 136);    // [256 n][2] (2048 B)
    const int n0 = sl * 256;

    if (t < 128) {
      const float4 v = *(const float4*)&x_out[((size_t)b * NN + n0) * 2 + t * 4];
      *(float4*)&psI[t * 4] = v;
    }
#pragma unroll
    for (int idx = t; idx < 2048; idx += 256) {
      const int o = idx >> 5, j4 = idx & 31;
      const float4 v = *(const float4*)&A[((size_t)b * OO + o) * JJ + j4 * 4];
      *(uint2*)&As_s[o * 136 + j4 * 4] = make_uint2(pack2(v.x, v.y), pack2(v.z, v.w));
    }
    const int w = t >> 6, L = t & 63;
    const int q4 = L >> 4, l15 = L & 15;
    const int nl = t & 63, q = t >> 6, br = q >> 1, half = q & 1;
    const int ot0 = (w & 1) * 32;
    const int nt0 = (w >> 1) * 32;
    __syncthreads();

    for (int s = 0; s < 4; ++s) {
      // basis: lane owns row n; exp(+i*2pi*m*p) by recurrence over m
      {
        const float p = psI[(s * 64 + nl) * 2 + br];
        const float fr = p - floorf(p);
        const float s1 = sin2pi(fr), c1 = cos2pi(fr);
        float brr = 1.f, bii = 0.f;
        if (half) {
          float r = c1, qq = s1;
#pragma unroll
          for (int k = 0; k < 4; ++k) { const float nr = r*r - qq*qq, ni = 2.f*r*qq; r = nr; qq = ni; }
          brr = r; bii = qq;
        }
        short* bp = &basn[nl * 136 + br * 64 + half * 32];
#pragma unroll
        for (int g2 = 0; g2 < 4; ++g2) {
          union { unsigned short u[8]; uint4 v; } P;
#pragma unroll
          for (int mi = 0; mi < 4; ++mi) {
            P.u[2 * mi]     = f2bf(brr);
            P.u[2 * mi + 1] = f2bf(bii);
            const float nr = brr * c1 - bii * s1, ni = brr * s1 + bii * c1;
            brr = nr; bii = ni;
          }
          *(uint4*)&bp[g2 * 8] = P.v;
        }
      }
      __syncthreads();
      f32x4 acc[4];
#pragma unroll
      for (int i = 0; i < 4; ++i) acc[i] = (f32x4){0.f, 0.f, 0.f, 0.f};
#pragma unroll
      for (int ks = 0; ks < 4; ++ks) {
        const int ko = ks * 32 + q4 * 8;
        const short8 a0 = *(const short8*)&As_s[(ot0 + l15) * 136 + ko];
        const short8 a1 = *(const short8*)&As_s[(ot0 + 16 + l15) * 136 + ko];
        const short8 b0 = *(const short8*)&basn[(nt0 + l15) * 136 + ko];
        const short8 b1 = *(const short8*)&basn[(nt0 + 16 + l15) * 136 + ko];
        acc[0] = __builtin_amdgcn_mfma_f32_16x16x32_bf16(a0, b0, acc[0], 0, 0, 0);
        acc[1] = __builtin_amdgcn_mfma_f32_16x16x32_bf16(a0, b1, acc[1], 0, 0, 0);
        acc[2] = __builtin_amdgcn_mfma_f32_16x16x32_bf16(a1, b0, acc[2], 0, 0, 0);
        acc[3] = __builtin_amdgcn_mfma_f32_16x16x32_bf16(a1, b1, acc[3], 0, 0, 0);
      }
      const int nbase = n0 + s * 64 + nt0 + l15;
#pragma unroll
      for (int oi = 0; oi < 2; ++oi)
#pragma unroll
        for (int ni = 0; ni < 2; ++ni) {
          const f32x4 v = acc[oi * 2 + ni];
#pragma unroll
          for (int r = 0; r < 4; ++r)
            out[((size_t)b * OO + ot0 + oi * 16 + q4 * 4 + r) * NN + nbase + ni * 16] = v[r];
        }
      __syncthreads();
    }
  }
}

extern "C" void kernel_launch(void* const* d_in, const int* in_sizes, int n_in,
                              void* d_out, int out_size, void* d_ws, size_t ws_size,
                              hipStream_t stream) {
  const float* x     = (const float*)d_in[0];
  const float* x_in  = (const float*)d_in[1];
  const float* x_out = (const float*)d_in[2];
  const float* w1    = (const float*)d_in[3];
  const float* w2    = (const float*)d_in[4];
  float* out = (float*)d_out;
  float* part = (float*)d_ws;                        // [B][64][J][C], 16 MB
  float* A    = part + (size_t)BB * 64 * JJ * CC;    // [B][O][J]
  unsigned* ctr = (unsigned*)(A + (size_t)BB * OO * JJ);

  hipMemsetAsync(ctr, 0, 64, stream);   // zero the barrier counter (8-byte need, 64 for alignment)
  fused_kernel<<<dim3(NBLK), 256, 0, stream>>>(x, x_in, x_out, w1, w2, out, part, A, ctr);
}

// Round 6
// 115.940 us; speedup vs baseline: 2.4910x; 2.4910x over previous
//
#include <hip/hip_runtime.h>

#define BB 8
#define CC 64
#define OO 64
#define NN 16384
#define MMODE 32
#define JJ 128
#define SFAC 64.0f

typedef __attribute__((ext_vector_type(8))) short short8;   // 8 bf16 = 4 VGPRs (MFMA A/B frag)
typedef __attribute__((ext_vector_type(4))) float f32x4;    // MFMA C/D frag

static __device__ __forceinline__ unsigned short f2bf(float f) {
  unsigned u = __float_as_uint(f);
  u += 0x7FFF + ((u >> 16) & 1);   // RTNE
  return (unsigned short)(u >> 16);
}
static __device__ __forceinline__ unsigned pack2(float a, float b) {
  return (unsigned)f2bf(a) | ((unsigned)f2bf(b) << 16);
}
// v_sin_f32/v_cos_f32 take REVOLUTIONS (D = sin(2*pi*S0))
static __device__ __forceinline__ float sin2pi(float x) { return __builtin_amdgcn_sinf(x); }
static __device__ __forceinline__ float cos2pi(float x) { return __builtin_amdgcn_cosf(x); }

// ws layout (floats):
//   part [B][64][J][C] at 0          (4,194,304 floats, 16 MB)
//   A    [B][O][J]     at 4,194,304  (65,536 floats)

// ---------------- forward NUFFT: part[b,sl,j,c] = sum_{n in 256-slab} bas[j,n]*x[c,n] ----------------
// One block per (256-n slab, b); all 64 channels -> each basis computed exactly once.
__global__ __launch_bounds__(256) void fwd_kernel(
    const float* __restrict__ x, const float* __restrict__ x_in,
    float* __restrict__ part) {
  __shared__ __attribute__((aligned(16))) short bas[JJ * 72];  // [j][n] bf16, stride 72 (18.4 KB)
  __shared__ __attribute__((aligned(16))) short xs[64 * 72];   // [c][n] bf16 (9.2 KB)
  __shared__ __attribute__((aligned(16))) float ps[512];       // x_in slab [256 n][2] (2 KB)
  const int t = threadIdx.x;
  const int b = blockIdx.y, sl = blockIdx.x;
  const int n0 = sl * 256;

  if (t < 128) {  // stage coords for whole slab (coalesced)
    const float4 v = *(const float4*)&x_in[((size_t)b * NN + n0) * 2 + t * 4];
    *(float4*)&ps[t * 4] = v;
  }
  // x loader: 64 c rows x 64 n per micro-slab, 4 float4/thread
  const int xc = t >> 2, xq = t & 3;
  const float* xbase = x + ((size_t)(b * CC + xc)) * NN + n0;
  float4 cur[4];
#pragma unroll
  for (int k = 0; k < 4; ++k) cur[k] = *(const float4*)&xbase[(k * 4 + xq) * 4];

  const int w = t >> 6, L = t & 63;
  const int q4 = L >> 4, l15 = L & 15;
  f32x4 acc[8];
#pragma unroll
  for (int i = 0; i < 8; ++i) acc[i] = (f32x4){0.f, 0.f, 0.f, 0.f};

  __syncthreads();  // ps visible

  for (int s = 0; s < 4; ++s) {
    // ---- stage x micro-slab (fp32 regs -> bf16 LDS) ----
#pragma unroll
    for (int k = 0; k < 4; ++k)
      *(uint2*)&xs[xc * 72 + (k * 4 + xq) * 4] =
          make_uint2(pack2(cur[k].x, cur[k].y), pack2(cur[k].z, cur[k].w));
    if (s < 3) {  // prefetch next micro-slab (overlaps basis gen + MFMA)
#pragma unroll
      for (int k = 0; k < 4; ++k)
        cur[k] = *(const float4*)&xbase[(s + 1) * 64 + (k * 4 + xq) * 4];
    }
    // ---- basis gen: exp(-i*2pi*m*p), revolutions-native HW sin/cos ----
#pragma unroll
    for (int ti = 0; ti < 2; ++ti) {
      const int tau = t + ti * 256;
      const int ng = tau & 7, mm = tau >> 3;
      const int br = mm >> 5, m = mm & 31;
      const float fm = (float)m;
      union { unsigned short u[8]; uint4 v; } R, I;
#pragma unroll
      for (int k = 0; k < 8; ++k) {
        const float p = ps[(s * 64 + ng * 8 + k) * 2 + br];
        float rev = fm * p;
        rev -= floorf(rev);
        R.u[k] = f2bf(cos2pi(rev));   // real = cos(2pi m p)
        I.u[k] = f2bf(-sin2pi(rev));  // imag = -sin(2pi m p)
      }
      const int row = br * 64 + 2 * m;
      *(uint4*)&bas[row * 72 + ng * 8]       = R.v;
      *(uint4*)&bas[(row + 1) * 72 + ng * 8] = I.v;
    }
    __syncthreads();
    // ---- MFMA: wave w owns j-tiles {2w,2w+1} x c-tiles {0..3} ----
#pragma unroll
    for (int ks = 0; ks < 2; ++ks) {
      const int ko = ks * 32 + q4 * 8;
      const short8 a0 = *(const short8*)&bas[(w * 32 + l15) * 72 + ko];
      const short8 a1 = *(const short8*)&bas[(w * 32 + 16 + l15) * 72 + ko];
#pragma unroll
      for (int ct = 0; ct < 4; ++ct) {
        const short8 bv = *(const short8*)&xs[(ct * 16 + l15) * 72 + ko];
        acc[ct]     = __builtin_amdgcn_mfma_f32_16x16x32_bf16(a0, bv, acc[ct], 0, 0, 0);
        acc[4 + ct] = __builtin_amdgcn_mfma_f32_16x16x32_bf16(a1, bv, acc[4 + ct], 0, 0, 0);
      }
    }
    __syncthreads();
  }
  // ---- epilogue: non-atomic partial store. C/D: col(c)=lane&15, row(j)=q4*4+reg ----
  float* pp = part + (size_t)(b * 64 + sl) * JJ * CC;
#pragma unroll
  for (int ai = 0; ai < 2; ++ai)
#pragma unroll
    for (int ct = 0; ct < 4; ++ct) {
      const f32x4 v = acc[ai * 4 + ct];
#pragma unroll
      for (int r = 0; r < 4; ++r)
        pp[(w * 32 + ai * 16 + q4 * 4 + r) * CC + ct * 16 + l15] = v[r];
    }
}

// ---------------- slab reduction + mode mixing ----------------
__global__ __launch_bounds__(256) void mix_kernel(
    const float* __restrict__ part, const float* __restrict__ w1,
    const float* __restrict__ w2, float* __restrict__ A) {
  __shared__ float red[8][64];
  __shared__ float fre[64], fim[64];
  const int m = blockIdx.x, branch = blockIdx.y, b = blockIdx.z;
  const int t = threadIdx.x;
  const int c = t & 63, g = t >> 6;
  const int jb = branch * 64 + 2 * m;
  // phase 1: reduce 64 slab partials for rows jb, jb+1
  float pre = 0.f, pim = 0.f;
#pragma unroll
  for (int k = 0; k < 16; ++k) {
    const int sl = g + 4 * k;
    const float* pp = part + (size_t)(b * 64 + sl) * JJ * CC;
    pre += pp[jb * CC + c];
    pim += pp[(jb + 1) * CC + c];
  }
  red[g * 2][c] = pre;
  red[g * 2 + 1][c] = pim;
  __syncthreads();
  if (t < 64) {
    fre[t] = red[0][t] + red[2][t] + red[4][t] + red[6][t];
    fim[t] = red[1][t] + red[3][t] + red[5][t] + red[7][t];
  }
  __syncthreads();
  // phase 2: complex GEMV over i, split 4 ways
  const float* w = branch ? w2 : w1;  // [i][o][m][2]
  float ar = 0.f, ai = 0.f;
#pragma unroll 4
  for (int ii = 0; ii < 16; ++ii) {
    const int i = g * 16 + ii;
    const float2 wv = *(const float2*)&w[(((size_t)i * 64 + c) * MMODE + m) * 2];
    ar += fre[i] * wv.x - fim[i] * wv.y;
    ai += fre[i] * wv.y + fim[i] * wv.x;
  }
  __syncthreads();
  red[g * 2][c] = ar;
  red[g * 2 + 1][c] = ai;
  __syncthreads();
  if (t < 64) {
    const float sr = red[0][t] + red[2][t] + red[4][t] + red[6][t];
    const float si = red[1][t] + red[3][t] + red[5][t] + red[7][t];
    // fold scale S=64 and Re(): out = A_re*cos + A_im*sin
    *(float2*)&A[((size_t)b * OO + t) * JJ + jb] = make_float2(SFAC * sr, -SFAC * si);
  }
}

// ---------------- inverse NUFFT: out[b,o,n] = sum_j A[o,j] * bas[n,j] ----------------
__global__ __launch_bounds__(256) void inv_kernel(
    const float* __restrict__ x_out, const float* __restrict__ A,
    float* __restrict__ out) {
  __shared__ __attribute__((aligned(16))) short As_s[OO * 136];  // [o][j] bf16, stride 136
  __shared__ __attribute__((aligned(16))) short basn[64 * 136];  // [n][j] bf16
  __shared__ __attribute__((aligned(16))) float psI[512];        // x_out slab [256 n][2]
  const int t = threadIdx.x;
  const int b = blockIdx.y;
  const int n0 = blockIdx.x * 256;

  if (t < 128) {
    const float4 v = *(const float4*)&x_out[((size_t)b * NN + n0) * 2 + t * 4];
    *(float4*)&psI[t * 4] = v;
  }
#pragma unroll
  for (int idx = t; idx < 2048; idx += 256) {   // A fp32 -> bf16 LDS, coalesced
    const int o = idx >> 5, j4 = idx & 31;
    const float4 v = *(const float4*)&A[((size_t)b * OO + o) * JJ + j4 * 4];
    *(uint2*)&As_s[o * 136 + j4 * 4] = make_uint2(pack2(v.x, v.y), pack2(v.z, v.w));
  }
  const int w = t >> 6, L = t & 63;
  const int q4 = L >> 4, l15 = L & 15;
  const int nl = t & 63, q = t >> 6, br = q >> 1, half = q & 1;
  const int ot0 = (w & 1) * 32;   // o rows: ot0 + {0..15, 16..31}
  const int nt0 = (w >> 1) * 32;  // n cols: nt0 + {0..15, 16..31}
  __syncthreads();

  for (int s = 0; s < 4; ++s) {
    // ---- basis gen: lane owns row n; exp(+i*2pi*m*p) by recurrence over m ----
    {
      const float p = psI[(s * 64 + nl) * 2 + br];
      const float fr = p - floorf(p);
      const float s1 = sin2pi(fr), c1 = cos2pi(fr);   // step = exp(+i*2pi*p)
      float brr = 1.f, bii = 0.f;
      if (half) {  // start at step^16 via 4 squarings
        float r = c1, qq = s1;
#pragma unroll
        for (int k = 0; k < 4; ++k) { const float nr = r*r - qq*qq, ni = 2.f*r*qq; r = nr; qq = ni; }
        brr = r; bii = qq;
      }
      short* bp = &basn[nl * 136 + br * 64 + half * 32];
#pragma unroll
      for (int g = 0; g < 4; ++g) {
        union { unsigned short u[8]; uint4 v; } P;
#pragma unroll
        for (int mi = 0; mi < 4; ++mi) {
          P.u[2 * mi]     = f2bf(brr);
          P.u[2 * mi + 1] = f2bf(bii);
          const float nr = brr * c1 - bii * s1, ni = brr * s1 + bii * c1;
          brr = nr; bii = ni;
        }
        *(uint4*)&bp[g * 8] = P.v;
      }
    }
    __syncthreads();
    f32x4 acc[4];
#pragma unroll
    for (int i = 0; i < 4; ++i) acc[i] = (f32x4){0.f, 0.f, 0.f, 0.f};
#pragma unroll
    for (int ks = 0; ks < 4; ++ks) {
      const int ko = ks * 32 + q4 * 8;
      const short8 a0 = *(const short8*)&As_s[(ot0 + l15) * 136 + ko];
      const short8 a1 = *(const short8*)&As_s[(ot0 + 16 + l15) * 136 + ko];
      const short8 b0 = *(const short8*)&basn[(nt0 + l15) * 136 + ko];
      const short8 b1 = *(const short8*)&basn[(nt0 + 16 + l15) * 136 + ko];
      acc[0] = __builtin_amdgcn_mfma_f32_16x16x32_bf16(a0, b0, acc[0], 0, 0, 0);
      acc[1] = __builtin_amdgcn_mfma_f32_16x16x32_bf16(a0, b1, acc[1], 0, 0, 0);
      acc[2] = __builtin_amdgcn_mfma_f32_16x16x32_bf16(a1, b0, acc[2], 0, 0, 0);
      acc[3] = __builtin_amdgcn_mfma_f32_16x16x32_bf16(a1, b1, acc[3], 0, 0, 0);
    }
    // ---- store: row o = ot0+oi*16+q4*4+r, col n = nt0+ni*16+l15 (64B segments) ----
    const int nbase = n0 + s * 64 + nt0 + l15;
#pragma unroll
    for (int oi = 0; oi < 2; ++oi)
#pragma unroll
      for (int ni = 0; ni < 2; ++ni) {
        const f32x4 v = acc[oi * 2 + ni];
#pragma unroll
        for (int r = 0; r < 4; ++r)
          out[((size_t)b * OO + ot0 + oi * 16 + q4 * 4 + r) * NN + nbase + ni * 16] = v[r];
      }
    __syncthreads();
  }
}

extern "C" void kernel_launch(void* const* d_in, const int* in_sizes, int n_in,
                              void* d_out, int out_size, void* d_ws, size_t ws_size,
                              hipStream_t stream) {
  const float* x     = (const float*)d_in[0];
  const float* x_in  = (const float*)d_in[1];
  const float* x_out = (const float*)d_in[2];
  const float* w1    = (const float*)d_in[3];
  const float* w2    = (const float*)d_in[4];
  float* out = (float*)d_out;
  float* part = (float*)d_ws;                        // [B][64][J][C], 16 MB
  float* A    = part + (size_t)BB * 64 * JJ * CC;    // [B][O][J]

  fwd_kernel<<<dim3(64, BB), 256, 0, stream>>>(x, x_in, part);
  mix_kernel<<<dim3(MMODE, 2, BB), 256, 0, stream>>>(part, w1, w2, A);
  inv_kernel<<<dim3(64, BB), 256, 0, stream>>>(x_out, A, out);
}

// Round 7
// 115.550 us; speedup vs baseline: 2.4994x; 1.0034x over previous
//
#include <hip/hip_runtime.h>

#define BB 8
#define CC 64
#define OO 64
#define NN 16384
#define MMODE 32
#define JJ 128
#define SFAC 64.0f

typedef __attribute__((ext_vector_type(8))) short short8;   // 8 bf16 = 4 VGPRs (MFMA A/B frag)
typedef __attribute__((ext_vector_type(4))) float f32x4;    // MFMA C/D frag

static __device__ __forceinline__ unsigned short f2bf(float f) {
  unsigned u = __float_as_uint(f);
  u += 0x7FFF + ((u >> 16) & 1);   // RTNE
  return (unsigned short)(u >> 16);
}
static __device__ __forceinline__ unsigned pack2(float a, float b) {
  return (unsigned)f2bf(a) | ((unsigned)f2bf(b) << 16);
}
static __device__ __forceinline__ float bf2f(unsigned short u) {
  return __uint_as_float(((unsigned)u) << 16);
}
// v_sin_f32/v_cos_f32 take REVOLUTIONS (D = sin(2*pi*S0))
static __device__ __forceinline__ float sin2pi(float x) { return __builtin_amdgcn_sinf(x); }
static __device__ __forceinline__ float cos2pi(float x) { return __builtin_amdgcn_cosf(x); }

// ws layout:
//   part (bf16) [B][64][J][C] at byte 0        (8 MB)
//   A    (f32)  [B][O][J]     at byte 8388608  (256 KB)

// ---------------- forward NUFFT: part[b,sl,j,c] = sum_{n in 256-slab} bas[j,n]*x[c,n] ----------------
__global__ __launch_bounds__(256) void fwd_kernel(
    const float* __restrict__ x, const float* __restrict__ x_in,
    unsigned short* __restrict__ part) {
  __shared__ __attribute__((aligned(16))) short bas[JJ * 72];  // [j][n] bf16, stride 72 (18.4 KB)
  __shared__ __attribute__((aligned(16))) short xs[64 * 72];   // [c][n] bf16 (9.2 KB)
  __shared__ __attribute__((aligned(16))) float ps[512];       // x_in slab [256 n][2] (2 KB)
  const int t = threadIdx.x;
  const int b = blockIdx.y, sl = blockIdx.x;
  const int n0 = sl * 256;

  if (t < 128) {  // stage coords for whole slab (coalesced)
    const float4 v = *(const float4*)&x_in[((size_t)b * NN + n0) * 2 + t * 4];
    *(float4*)&ps[t * 4] = v;
  }
  // x loader: 64 c rows x 64 n per micro-slab, 4 float4/thread
  const int xc = t >> 2, xq = t & 3;
  const float* xbase = x + ((size_t)(b * CC + xc)) * NN + n0;
  float4 cur[4];
#pragma unroll
  for (int k = 0; k < 4; ++k) cur[k] = *(const float4*)&xbase[(k * 4 + xq) * 4];

  const int w = t >> 6, L = t & 63;
  const int q4 = L >> 4, l15 = L & 15;
  f32x4 acc[8];
#pragma unroll
  for (int i = 0; i < 8; ++i) acc[i] = (f32x4){0.f, 0.f, 0.f, 0.f};

  __syncthreads();  // ps visible

  for (int s = 0; s < 4; ++s) {
    // ---- stage x micro-slab (fp32 regs -> bf16 LDS) ----
#pragma unroll
    for (int k = 0; k < 4; ++k)
      *(uint2*)&xs[xc * 72 + (k * 4 + xq) * 4] =
          make_uint2(pack2(cur[k].x, cur[k].y), pack2(cur[k].z, cur[k].w));
    if (s < 3) {  // prefetch next micro-slab (overlaps basis gen + MFMA)
#pragma unroll
      for (int k = 0; k < 4; ++k)
        cur[k] = *(const float4*)&xbase[(s + 1) * 64 + (k * 4 + xq) * 4];
    }
    // ---- basis gen: exp(-i*2pi*m*p), revolutions-native HW sin/cos ----
#pragma unroll
    for (int ti = 0; ti < 2; ++ti) {
      const int tau = t + ti * 256;
      const int ng = tau & 7, mm = tau >> 3;
      const int br = mm >> 5, m = mm & 31;
      const float fm = (float)m;
      union { unsigned short u[8]; uint4 v; } R, I;
#pragma unroll
      for (int k = 0; k < 8; ++k) {
        const float p = ps[(s * 64 + ng * 8 + k) * 2 + br];
        float rev = fm * p;
        rev -= floorf(rev);
        R.u[k] = f2bf(cos2pi(rev));   // real = cos(2pi m p)
        I.u[k] = f2bf(-sin2pi(rev));  // imag = -sin(2pi m p)
      }
      const int row = br * 64 + 2 * m;
      *(uint4*)&bas[row * 72 + ng * 8]       = R.v;
      *(uint4*)&bas[(row + 1) * 72 + ng * 8] = I.v;
    }
    __syncthreads();
    // ---- MFMA: wave w owns j-tiles {2w,2w+1} x c-tiles {0..3} ----
#pragma unroll
    for (int ks = 0; ks < 2; ++ks) {
      const int ko = ks * 32 + q4 * 8;
      const short8 a0 = *(const short8*)&bas[(w * 32 + l15) * 72 + ko];
      const short8 a1 = *(const short8*)&bas[(w * 32 + 16 + l15) * 72 + ko];
#pragma unroll
      for (int ct = 0; ct < 4; ++ct) {
        const short8 bv = *(const short8*)&xs[(ct * 16 + l15) * 72 + ko];
        acc[ct]     = __builtin_amdgcn_mfma_f32_16x16x32_bf16(a0, bv, acc[ct], 0, 0, 0);
        acc[4 + ct] = __builtin_amdgcn_mfma_f32_16x16x32_bf16(a1, bv, acc[4 + ct], 0, 0, 0);
      }
    }
    __syncthreads();
  }
  // ---- epilogue: non-atomic bf16 partial store. C/D: col(c)=lane&15, row(j)=q4*4+reg ----
  unsigned short* pp = part + (size_t)(b * 64 + sl) * JJ * CC;
#pragma unroll
  for (int ai = 0; ai < 2; ++ai)
#pragma unroll
    for (int ct = 0; ct < 4; ++ct) {
      const f32x4 v = acc[ai * 4 + ct];
#pragma unroll
      for (int r = 0; r < 4; ++r)
        pp[(w * 32 + ai * 16 + q4 * 4 + r) * CC + ct * 16 + l15] = f2bf(v[r]);
    }
}

// ---------------- slab reduction + mode mixing ----------------
__global__ __launch_bounds__(256) void mix_kernel(
    const unsigned short* __restrict__ part, const float* __restrict__ w1,
    const float* __restrict__ w2, float* __restrict__ A) {
  __shared__ float red[8][64];
  __shared__ float fre[64], fim[64];
  const int m = blockIdx.x, branch = blockIdx.y, b = blockIdx.z;
  const int t = threadIdx.x;
  const int c = t & 63, g = t >> 6;
  const int jb = branch * 64 + 2 * m;
  // phase 1: reduce 64 slab partials for rows jb, jb+1
  float pre = 0.f, pim = 0.f;
#pragma unroll
  for (int k = 0; k < 16; ++k) {
    const int sl = g + 4 * k;
    const unsigned short* pp = part + (size_t)(b * 64 + sl) * JJ * CC;
    pre += bf2f(pp[jb * CC + c]);
    pim += bf2f(pp[(jb + 1) * CC + c]);
  }
  red[g * 2][c] = pre;
  red[g * 2 + 1][c] = pim;
  __syncthreads();
  if (t < 64) {
    fre[t] = red[0][t] + red[2][t] + red[4][t] + red[6][t];
    fim[t] = red[1][t] + red[3][t] + red[5][t] + red[7][t];
  }
  __syncthreads();
  // phase 2: complex GEMV over i, split 4 ways
  const float* w = branch ? w2 : w1;  // [i][o][m][2]
  float ar = 0.f, ai = 0.f;
#pragma unroll 4
  for (int ii = 0; ii < 16; ++ii) {
    const int i = g * 16 + ii;
    const float2 wv = *(const float2*)&w[(((size_t)i * 64 + c) * MMODE + m) * 2];
    ar += fre[i] * wv.x - fim[i] * wv.y;
    ai += fre[i] * wv.y + fim[i] * wv.x;
  }
  __syncthreads();
  red[g * 2][c] = ar;
  red[g * 2 + 1][c] = ai;
  __syncthreads();
  if (t < 64) {
    const float sr = red[0][t] + red[2][t] + red[4][t] + red[6][t];
    const float si = red[1][t] + red[3][t] + red[5][t] + red[7][t];
    // fold scale S=64 and Re(): out = A_re*cos + A_im*sin
    *(float2*)&A[((size_t)b * OO + t) * JJ + jb] = make_float2(SFAC * sr, -SFAC * si);
  }
}

// ---------------- inverse NUFFT: out[b,o,n] = sum_j A[o,j] * bas[n,j] ----------------
__global__ __launch_bounds__(256) void inv_kernel(
    const float* __restrict__ x_out, const float* __restrict__ A,
    float* __restrict__ out) {
  __shared__ __attribute__((aligned(16))) short As_s[OO * 136];  // [o][j] bf16, stride 136
  __shared__ __attribute__((aligned(16))) short basn[64 * 136];  // [n][j] bf16
  __shared__ __attribute__((aligned(16))) float psI[512];        // x_out slab [256 n][2]
  const int t = threadIdx.x;
  const int b = blockIdx.y;
  const int n0 = blockIdx.x * 256;

  if (t < 128) {
    const float4 v = *(const float4*)&x_out[((size_t)b * NN + n0) * 2 + t * 4];
    *(float4*)&psI[t * 4] = v;
  }
#pragma unroll
  for (int idx = t; idx < 2048; idx += 256) {   // A fp32 -> bf16 LDS, coalesced
    const int o = idx >> 5, j4 = idx & 31;
    const float4 v = *(const float4*)&A[((size_t)b * OO + o) * JJ + j4 * 4];
    *(uint2*)&As_s[o * 136 + j4 * 4] = make_uint2(pack2(v.x, v.y), pack2(v.z, v.w));
  }
  const int w = t >> 6, L = t & 63;
  const int q4 = L >> 4, l15 = L & 15;
  const int nl = t & 63, q = t >> 6, br = q >> 1, half = q & 1;
  const int ot0 = (w & 1) * 32;   // o rows: ot0 + {0..15, 16..31}
  const int nt0 = (w >> 1) * 32;  // n cols: nt0 + {0..15, 16..31}
  __syncthreads();

  for (int s = 0; s < 4; ++s) {
    // ---- basis gen: lane owns row n; exp(+i*2pi*m*p) by recurrence over m ----
    {
      const float p = psI[(s * 64 + nl) * 2 + br];
      const float fr = p - floorf(p);
      const float s1 = sin2pi(fr), c1 = cos2pi(fr);   // step = exp(+i*2pi*p)
      float brr = 1.f, bii = 0.f;
      if (half) {  // start at step^16 via 4 squarings
        float r = c1, qq = s1;
#pragma unroll
        for (int k = 0; k < 4; ++k) { const float nr = r*r - qq*qq, ni = 2.f*r*qq; r = nr; qq = ni; }
        brr = r; bii = qq;
      }
      short* bp = &basn[nl * 136 + br * 64 + half * 32];
#pragma unroll
      for (int g = 0; g < 4; ++g) {
        union { unsigned short u[8]; uint4 v; } P;
#pragma unroll
        for (int mi = 0; mi < 4; ++mi) {
          P.u[2 * mi]     = f2bf(brr);
          P.u[2 * mi + 1] = f2bf(bii);
          const float nr = brr * c1 - bii * s1, ni = brr * s1 + bii * c1;
          brr = nr; bii = ni;
        }
        *(uint4*)&bp[g * 8] = P.v;
      }
    }
    __syncthreads();
    f32x4 acc[4];
#pragma unroll
    for (int i = 0; i < 4; ++i) acc[i] = (f32x4){0.f, 0.f, 0.f, 0.f};
#pragma unroll
    for (int ks = 0; ks < 4; ++ks) {
      const int ko = ks * 32 + q4 * 8;
      const short8 a0 = *(const short8*)&As_s[(ot0 + l15) * 136 + ko];
      const short8 a1 = *(const short8*)&As_s[(ot0 + 16 + l15) * 136 + ko];
      const short8 b0 = *(const short8*)&basn[(nt0 + l15) * 136 + ko];
      const short8 b1 = *(const short8*)&basn[(nt0 + 16 + l15) * 136 + ko];
      acc[0] = __builtin_amdgcn_mfma_f32_16x16x32_bf16(a0, b0, acc[0], 0, 0, 0);
      acc[1] = __builtin_amdgcn_mfma_f32_16x16x32_bf16(a0, b1, acc[1], 0, 0, 0);
      acc[2] = __builtin_amdgcn_mfma_f32_16x16x32_bf16(a1, b0, acc[2], 0, 0, 0);
      acc[3] = __builtin_amdgcn_mfma_f32_16x16x32_bf16(a1, b1, acc[3], 0, 0, 0);
    }
    // ---- store: row o = ot0+oi*16+q4*4+r, col n = nt0+ni*16+l15 (64B segments) ----
    const int nbase = n0 + s * 64 + nt0 + l15;
#pragma unroll
    for (int oi = 0; oi < 2; ++oi)
#pragma unroll
      for (int ni = 0; ni < 2; ++ni) {
        const f32x4 v = acc[oi * 2 + ni];
#pragma unroll
        for (int r = 0; r < 4; ++r)
          out[((size_t)b * OO + ot0 + oi * 16 + q4 * 4 + r) * NN + nbase + ni * 16] = v[r];
      }
    __syncthreads();
  }
}

extern "C" void kernel_launch(void* const* d_in, const int* in_sizes, int n_in,
                              void* d_out, int out_size, void* d_ws, size_t ws_size,
                              hipStream_t stream) {
  const float* x     = (const float*)d_in[0];
  const float* x_in  = (const float*)d_in[1];
  const float* x_out = (const float*)d_in[2];
  const float* w1    = (const float*)d_in[3];
  const float* w2    = (const float*)d_in[4];
  float* out = (float*)d_out;
  unsigned short* part = (unsigned short*)d_ws;                 // bf16 [B][64][J][C], 8 MB
  float* A = (float*)((char*)d_ws + (size_t)BB * 64 * JJ * CC * sizeof(unsigned short));

  fwd_kernel<<<dim3(64, BB), 256, 0, stream>>>(x, x_in, part);
  mix_kernel<<<dim3(MMODE, 2, BB), 256, 0, stream>>>(part, w1, w2, A);
  inv_kernel<<<dim3(64, BB), 256, 0, stream>>>(x_out, A, out);
}